// Round 20
// baseline (92.466 us; speedup 1.0000x reference)
//
#include <hip/hip_runtime.h>
#include <hip/hip_bf16.h>
#include <math.h>

// B=16, C=64, CQ=8, H=W=128
typedef unsigned short u16;
typedef unsigned int u32;
typedef __attribute__((ext_vector_type(8))) short    bf16x8;
typedef __attribute__((ext_vector_type(8))) unsigned short us8;
typedef __attribute__((ext_vector_type(4))) unsigned short us4;
typedef __attribute__((ext_vector_type(4))) float    f32x4;
typedef __attribute__((ext_vector_type(4))) unsigned int u32x4;
typedef __attribute__((ext_vector_type(2))) unsigned int u32x2;

__device__ __forceinline__ u16 f2bf(float f) {
    unsigned u = __float_as_uint(f);
    return (u16)((u + 0x7FFFu + ((u >> 16) & 1u)) >> 16);
}
__device__ __forceinline__ float bf2f(u16 v) {
    return __uint_as_float((unsigned)v << 16);
}
// Pack 2 floats -> 2 bf16 (round-half-up) in 3 VALU ops via v_perm_b32.
__device__ __forceinline__ u32 pk2bf(float lo, float hi) {
    u32 a = __float_as_uint(lo) + 0x8000u;
    u32 b = __float_as_uint(hi) + 0x8000u;
    return __builtin_amdgcn_perm(b, a, 0x07060302u);  // [b.b3 b.b2 a.b3 a.b2]
}

// ---------------------------------------------------------------------------
// Kernel 0: W prep. Wpk[nt(5)][kt(2)][lane(64)][8]; biasf[80] = {bv,bq,bk}.
// q rows (n in [64,72)) and bq are pre-scaled by log2(e) so the attention
// kernels can use exp2 instead of exp.
// ---------------------------------------------------------------------------
__global__ __launch_bounds__(256) void wprep_kernel(
    const float* __restrict__ Wq, const float* __restrict__ bq,
    const float* __restrict__ Wk, const float* __restrict__ bk,
    const float* __restrict__ Wv, const float* __restrict__ bv,
    u16* __restrict__ Wpk, float* __restrict__ biasf)
{
    const float LOG2E = 1.44269504088896340736f;
    int t = threadIdx.x;
    for (int s = t; s < 640; s += 256) {
        int nt = s >> 7;
        int kt = (s >> 6) & 1;
        int l  = s & 63;
        int n  = (nt << 4) | (l & 15);
        int k0 = kt * 32 + ((l >> 4) << 3);
        const float* row;
        float sc = 1.0f;
        if (n < 64) row = Wv + n * 64;
        else if (n < 72) { row = Wq + (n - 64) * 64; sc = LOG2E; }
        else row = Wk + (n - 72) * 64;
        us8 o;
#pragma unroll
        for (int j = 0; j < 8; j++) o[j] = f2bf(row[k0 + j] * sc);
        *(us8*)&Wpk[s * 8] = o;
    }
    if (t < 80) {
        float bb;
        if (t < 64) bb = bv[t];
        else if (t < 72) bb = bq[t - 64] * LOG2E;
        else bb = bk[t - 72];
        biasf[t] = bb;
    }
}

// ---------------------------------------------------------------------------
// Kernel 1: projections via MFMA. 8h x 16w tile, 2048 blocks x 256 thr.
// Outputs ONLY vTc2[b][oct][w][c][g8] and qkTr[b][h][w][16].
// ---------------------------------------------------------------------------
__global__ __launch_bounds__(256) void proj_kernel(
    const float* __restrict__ x, const u16* __restrict__ Wpk,
    const float* __restrict__ biasf,
    u16* __restrict__ vTc2, u16* __restrict__ qkTr)
{
    __shared__ u16 vstage[16 * 65 * 8];   // 16.25 KB: [w16][c64+1pad][g8]
    __shared__ u16 qstage[4][32 * 16];    // 4 KB

    int t = threadIdx.x;
    int bid = blockIdx.x;
    int wg = ((bid & 7) << 8) | (bid >> 3);   // bijective (2048 = 8*256)
    int b = wg >> 7;
    int hg = (wg >> 3) & 15;                  // h-oct 0..15
    int wq = wg & 7;
    int h0 = hg << 3, w0 = wq << 4;
    const float* xb = x + ((long)b << 20);

    int wv = t >> 6, l = t & 63;
    int m16 = l & 15, kg = l >> 4;

    // ---- A-frags direct from global: m-tile mt -> h-row h0+wv*2+mt ----
    bf16x8 af[2][2];
#pragma unroll
    for (int mt = 0; mt < 2; mt++) {
        int base = ((h0 + wv * 2 + mt) << 7) + w0 + m16;
#pragma unroll
        for (int kt = 0; kt < 2; kt++) {
            float v[8];
#pragma unroll
            for (int j = 0; j < 8; j++)
                v[j] = xb[((kt * 32 + (kg << 3) + j) << 14) + base];
            u32x4 a4 = { pk2bf(v[0], v[1]), pk2bf(v[2], v[3]),
                         pk2bf(v[4], v[5]), pk2bf(v[6], v[7]) };
            af[mt][kt] = __builtin_bit_cast(bf16x8, a4);
        }
    }

    f32x4 acc[2][5];
#pragma unroll
    for (int nt = 0; nt < 5; nt++) {
        float bb = biasf[(nt << 4) + m16];
        f32x4 binit = {bb, bb, bb, bb};
        bf16x8 b0 = *(const bf16x8*)&Wpk[(((nt << 1) + 0) << 9) + (l << 3)];
        bf16x8 b1 = *(const bf16x8*)&Wpk[(((nt << 1) + 1) << 9) + (l << 3)];
#pragma unroll
        for (int mt = 0; mt < 2; mt++) {
            f32x4 a_ = binit;
            a_ = __builtin_amdgcn_mfma_f32_16x16x32_bf16(af[mt][0], b0, a_, 0, 0, 0);
            a_ = __builtin_amdgcn_mfma_f32_16x16x32_bf16(af[mt][1], b1, a_, 0, 0, 0);
            acc[mt][nt] = a_;
        }
    }

    // ---- vstage: u32 = {g=wv*2 (mt0), g=wv*2+1 (mt1)} at [wl][c] ----
#pragma unroll
    for (int nt = 0; nt < 4; nt++) {
#pragma unroll
        for (int r = 0; r < 4; r++) {
            int c = (nt << 4) + m16;
            int wl = (kg << 2) + r;
            u32 pkv = pk2bf(acc[0][nt][r], acc[1][nt][r]);
            *(u32*)((char*)vstage + wl * 1040 + c * 16 + wv * 4) = pkv;
        }
    }

    // ---- qk: wave-local LDS transpose -> 2x512B coalesced stores ----
    {
        u16* qs = qstage[wv];
#pragma unroll
        for (int mt = 0; mt < 2; mt++) {
#pragma unroll
            for (int r = 0; r < 4; r++)
                qs[((mt << 4) + (kg << 2) + r) * 16 + m16] = f2bf(acc[mt][4][r]);
        }
        int pixl = l >> 1, half = l & 1;
        us8 o = *(us8*)&qs[pixl * 16 + half * 8];
        int hgl = h0 + wv * 2 + (pixl >> 4);
        int wgl = w0 + (pixl & 15);
        *(us8*)&qkTr[(((long)((b << 14) + hgl * 128 + wgl)) << 4) + half * 8] = o;
    }
    __syncthreads();

    // ---- vTc2 write-out: 4 iters, 1KB contiguous per wave-instr ----
#pragma unroll
    for (int u = 0; u < 4; u++) {
        int lin = (u << 8) + t;
        int c = lin & 63, wl = lin >> 6;
        us8 vv = *(const us8*)((char*)vstage + wl * 1040 + c * 16);
        long dst = ((((long)(b * 16 + hg)) * 128 + w0 + wl) * 64 + c) << 3;
        *(us8*)&vTc2[dst] = vv;
    }
}

// ---------------------------------------------------------------------------
// Kernel 3: column attention, h-split. Block (b, w, hh); 4096 blocks.
// Vs global loads issued EARLY (pinned), LDS-written after QK^T (T14).
// ---------------------------------------------------------------------------
__global__ __launch_bounds__(512) void colH_kernel(
    const u16* __restrict__ qkTr, const u16* __restrict__ vTc2,
    u16* __restrict__ accHt, float* __restrict__ sH)
{
    __shared__ u16 Qpk[65 * 8];
    __shared__ u16 Kpk[129 * 8];
    __shared__ u16 Epk[1024 * 8];      // 16 KB
    __shared__ u16 Vs[1024 * 8];       // 16 KB

    int t = threadIdx.x;
    int bid = blockIdx.x;
    int wg = ((bid & 7) << 9) | (bid >> 3);
    int b = wg >> 8, w = (wg >> 1) & 127, hh = wg & 1;
    int h0 = hh << 6;

    // ---- issue Vs loads early (2 us8 per thread) ----
    us8 vv0, vv1;
    {
        int m0 = t, m1 = t + 512;
        int c0 = m0 >> 4, s0 = m0 & 15;
        int o0 = (s0 & 8) | ((s0 ^ c0) & 7);
        vv0 = *(const us8*)(vTc2 + ((((long)(b * 16 + o0)) * 128 + w) * 64 + c0) * 8);
        int c1 = m1 >> 4, s1 = m1 & 15;
        int o1 = (s1 & 8) | ((s1 ^ c1) & 7);
        vv1 = *(const us8*)(vTc2 + ((((long)(b * 16 + o1)) * 128 + w) * 64 + c1) * 8);
    }
    {
        uint4 p0 = *(uint4*)&vv0, p1 = *(uint4*)&vv1;
        asm volatile("" :: "v"(p0.x), "v"(p0.y), "v"(p0.z), "v"(p0.w),
                          "v"(p1.x), "v"(p1.y), "v"(p1.z), "v"(p1.w));
    }

    if (t < 64) {
        const u16* p = qkTr + (((long)((b << 14) + (h0 + t) * 128 + w)) << 4);
        *(us8*)&Qpk[t * 8] = *(const us8*)p;
    } else if (t == 64) {
        us8 z = {0,0,0,0,0,0,0,0};
        *(us8*)&Qpk[64 * 8] = z;
    } else if (t >= 128 && t < 256) {
        const u16* p = qkTr + (((long)((b << 14) + (t - 128) * 128 + w)) << 4);
        *(us8*)&Kpk[(t - 128) * 8] = *(const us8*)(p + 8);
    } else if (t == 256) {
        us8 z = {0,0,0,0,0,0,0,0};
        *(us8*)&Kpk[128 * 8] = z;
    }
    __syncthreads();   // Qpk/Kpk ready

    int wv = t >> 6, l = t & 63;
    int m16 = l & 15, kg = l >> 4;
    f32x4 zero4 = {0.f, 0.f, 0.f, 0.f};

    // ---- QK^T: wave owns g-tile gt=wv; E[g][h0+ht*16+m16], 4 ht ----
    int gt = wv;
    bf16x8 afr;
    { int sl = (kg == 0) ? (gt * 16 + m16) : 128;
      afr = *(const bf16x8*)&Kpk[sl * 8]; }
    int kgr = ((gt & 1) << 1) | (kg >> 1);
    int jb  = (kg & 1) << 2;
    int gbase = gt * 16 + kg * 4;
#pragma unroll
    for (int ht = 0; ht < 4; ht++) {
        int slB = (kg == 0) ? (ht * 16 + m16) : 64;
        bf16x8 bfr = *(const bf16x8*)&Qpk[slB * 8];
        f32x4 e = __builtin_amdgcn_mfma_f32_16x16x32_bf16(afr, bfr, zero4, 0, 0, 0);
        float vf[4];
#pragma unroll
        for (int r = 0; r < 4; r++) {
            int g = gbase + r, h = h0 + ht * 16 + m16;
            vf[r] = (g == h) ? 0.f : exp2f(e[r]);
        }
        int eidx = ((((ht << 2) | (gt >> 1)) * 64 + kgr * 16 + m16) << 3) + jb;
        u32x2 pk2;
        pk2.x = pk2bf(vf[0], vf[1]);
        pk2.y = pk2bf(vf[2], vf[3]);
        *(u32x2*)&Epk[eidx] = pk2;
    }

    // ---- Vs LDS writes (loads have had QK^T to land) ----
    *(us8*)&Vs[t << 3] = vv0;
    *(us8*)&Vs[(t + 512) << 3] = vv1;
    __syncthreads();

    // ---- PV: wave (cp, hq): c-tiles {2cp,2cp+1}, h-tile hq ----
    int cp = wv >> 2, hq = wv & 3;
    bf16x8 bE[4];
#pragma unroll
    for (int kt = 0; kt < 4; kt++)
        bE[kt] = *(const bf16x8*)&Epk[(((hq << 2) + kt) * 64 + l) << 3];

    f32x4 acc[2];
    acc[0] = zero4; acc[1] = zero4;
#pragma unroll
    for (int ci = 0; ci < 2; ci++) {
        int ct = cp * 2 + ci;
#pragma unroll
        for (int kt = 0; kt < 4; kt++) {
            int slot = ((ct * 16 + m16) << 4) | ((((kt << 2) | kg)) ^ (m16 & 7));
            bf16x8 aV = *(const bf16x8*)&Vs[slot << 3];
            acc[ci] = __builtin_amdgcn_mfma_f32_16x16x32_bf16(aV, bE[kt], acc[ci], 0, 0, 0);
        }
    }
    f32x4 accS = zero4;
    if (cp == 0) {
        bf16x8 ones;
        short ov = (m16 == 0) ? (short)0x3F80 : (short)0;
#pragma unroll
        for (int j = 0; j < 8; j++) ones[j] = ov;
#pragma unroll
        for (int kt = 0; kt < 4; kt++)
            accS = __builtin_amdgcn_mfma_f32_16x16x32_bf16(ones, bE[kt], accS, 0, 0, 0);
    }

    // ---- epilogue: shfl-repack -> one us8 store per lane ----
    u32x2 pk[2];
#pragma unroll
    for (int ci = 0; ci < 2; ci++) {
        pk[ci].x = pk2bf(acc[ci][0], acc[ci][1]);
        pk[ci].y = pk2bf(acc[ci][2], acc[ci][3]);
    }
    int q = l & 3, hrow = l >> 2;
    int sA = ((q & 1) << 5) | hrow;
    int sB = sA + 16;
    unsigned a0 = __shfl(pk[0].x, sA, 64), a1 = __shfl(pk[0].y, sA, 64);
    unsigned a2 = __shfl(pk[1].x, sA, 64), a3 = __shfl(pk[1].y, sA, 64);
    unsigned b0 = __shfl(pk[0].x, sB, 64), b1 = __shfl(pk[0].y, sB, 64);
    unsigned b2 = __shfl(pk[1].x, sB, 64), b3 = __shfl(pk[1].y, sB, 64);
    int cisel = q >> 1;
    uint4 o;
    o.x = cisel ? a2 : a0;  o.y = cisel ? a3 : a1;
    o.z = cisel ? b2 : b0;  o.w = cisel ? b3 : b1;
    long oaddr = (((long)(b * 128 + w)) * 128 + h0 + hq * 16 + hrow) * 64
               + cp * 32 + q * 8;
    *(uint4*)&accHt[oaddr] = o;

    if (cp == 0 && kg == 0)
        sH[(b * 128 + w) * 128 + h0 + hq * 16 + m16] = accS[0];
}

// ---------------------------------------------------------------------------
// Kernel 4: row attention + fused finalize + in-block V-compute.
// Phase order: issue all global loads -> stage Q/K -> barrier -> QK^T ->
// V-GEMM (loads landed under QK^T) -> Vs write -> barrier -> PV -> epilogue.
// ---------------------------------------------------------------------------
__global__ __launch_bounds__(512) void rowW_fin_kernel(
    const u16* __restrict__ qkTr, const u16* __restrict__ Wpk,
    const float* __restrict__ biasf,
    const u16* __restrict__ accHt, const float* __restrict__ sH,
    const float* __restrict__ x, const float* __restrict__ gamma,
    float* __restrict__ out)
{
    __shared__ u16 Qpk[65 * 8];
    __shared__ u16 Kpk[129 * 8];
    __shared__ u16 Epk[1024 * 8];   // 16 KB
    __shared__ u16 Vs[1024 * 8];    // 16 KB

    int t = threadIdx.x;
    int bid = blockIdx.x;
    int wg = ((bid & 7) << 9) | (bid >> 3);
    int b = wg >> 8, h = (wg >> 1) & 127, wh = wg & 1;
    int w0 = wh << 6;
    float gm = gamma[0];

    int wv = t >> 6, l = t & 63;
    int m16 = l & 15, kg = l >> 4;
    int cp = wv >> 2, hq = wv & 3;
    int wcol = hq * 16 + m16;
    int wfull = w0 + wcol;

    const float* xrow = x + ((long)b << 20) + (h << 7);

    // ---- hoisted finalize loads ----
    float sHreg = sH[((long)(b * 128 + wfull)) * 128 + h];
    uint4 hAw;
    {
        long hb = (((long)(b * 128 + w0 + (hq << 4) + (l >> 2))) * 128 + h) * 64
                + cp * 32 + ((l & 3) << 3);
        hAw = *(const uint4*)&accHt[hb];
    }
    float xr[2][4];
#pragma unroll
    for (int ci = 0; ci < 2; ci++)
#pragma unroll
        for (int r = 0; r < 4; r++)
            xr[ci][r] = xrow[((long)(cp * 32 + ci * 16 + (kg << 2) + r) << 14) + wfull];

    // ---- issue V-frag loads early ----
    float vfr[2][8];
#pragma unroll
    for (int kt = 0; kt < 2; kt++)
#pragma unroll
        for (int j = 0; j < 8; j++)
            vfr[kt][j] = xrow[((long)(kt * 32 + (kg << 3) + j) << 14) + (wv << 4) + m16];

    // keep-alive pins (rule #17)
    asm volatile("" :: "v"(sHreg), "v"(hAw.x), "v"(hAw.y), "v"(hAw.z), "v"(hAw.w));
    asm volatile("" :: "v"(xr[0][0]), "v"(xr[0][1]), "v"(xr[0][2]), "v"(xr[0][3]),
                      "v"(xr[1][0]), "v"(xr[1][1]), "v"(xr[1][2]), "v"(xr[1][3]));
    asm volatile("" :: "v"(vfr[0][0]), "v"(vfr[0][1]), "v"(vfr[0][2]), "v"(vfr[0][3]),
                      "v"(vfr[0][4]), "v"(vfr[0][5]), "v"(vfr[0][6]), "v"(vfr[0][7]));
    asm volatile("" :: "v"(vfr[1][0]), "v"(vfr[1][1]), "v"(vfr[1][2]), "v"(vfr[1][3]),
                      "v"(vfr[1][4]), "v"(vfr[1][5]), "v"(vfr[1][6]), "v"(vfr[1][7]));

    // ---- staging: Qpk/Kpk ----
    if (t < 64) {
        const u16* p = qkTr + (((long)((b << 14) + h * 128 + w0 + t)) << 4);
        *(us8*)&Qpk[t * 8] = *(const us8*)p;
    } else if (t == 64) {
        us8 z = {0,0,0,0,0,0,0,0};
        *(us8*)&Qpk[64 * 8] = z;
    } else if (t >= 128 && t < 256) {
        const u16* p = qkTr + (((long)((b << 14) + h * 128 + (t - 128))) << 4);
        *(us8*)&Kpk[(t - 128) * 8] = *(const us8*)(p + 8);
    } else if (t == 256) {
        us8 z = {0,0,0,0,0,0,0,0};
        *(us8*)&Kpk[128 * 8] = z;
    }
    __syncthreads();   // Qpk/Kpk ready

    f32x4 zero4 = {0.f, 0.f, 0.f, 0.f};

    // ---- QK^T: wave owns v-tile gt=wv; E[v][w0+ht*16+m16], no mask ----
    int gt = wv;
    bf16x8 afr;
    { int sl = (kg == 0) ? (gt * 16 + m16) : 128;
      afr = *(const bf16x8*)&Kpk[sl * 8]; }
    int kgr = ((gt & 1) << 1) | (kg >> 1);
    int jb  = (kg & 1) << 2;
#pragma unroll
    for (int ht = 0; ht < 4; ht++) {
        int slB = (kg == 0) ? (ht * 16 + m16) : 64;
        bf16x8 bfr = *(const bf16x8*)&Qpk[slB * 8];
        f32x4 e = __builtin_amdgcn_mfma_f32_16x16x32_bf16(afr, bfr, zero4, 0, 0, 0);
        float vf[4];
#pragma unroll
        for (int r = 0; r < 4; r++) vf[r] = exp2f(e[r]);
        int eidx = ((((ht << 2) | (gt >> 1)) * 64 + kgr * 16 + m16) << 3) + jb;
        u32x2 pk2;
        pk2.x = pk2bf(vf[0], vf[1]);
        pk2.y = pk2bf(vf[2], vf[3]);
        *(u32x2*)&Epk[eidx] = pk2;
    }

    // ---- V-GEMM (loads landed under QK^T) ----
    {
        bf16x8 xa[2];
#pragma unroll
        for (int kt = 0; kt < 2; kt++) {
            u32x4 a4 = { pk2bf(vfr[kt][0], vfr[kt][1]), pk2bf(vfr[kt][2], vfr[kt][3]),
                         pk2bf(vfr[kt][4], vfr[kt][5]), pk2bf(vfr[kt][6], vfr[kt][7]) };
            xa[kt] = __builtin_bit_cast(bf16x8, a4);
        }
#pragma unroll
        for (int nt = 0; nt < 4; nt++) {
            float bb = biasf[(nt << 4) + m16];
            f32x4 a_ = {bb, bb, bb, bb};
            bf16x8 b0 = *(const bf16x8*)&Wpk[(((nt << 1) + 0) << 9) + (l << 3)];
            bf16x8 b1 = *(const bf16x8*)&Wpk[(((nt << 1) + 1) << 9) + (l << 3)];
            a_ = __builtin_amdgcn_mfma_f32_16x16x32_bf16(xa[0], b0, a_, 0, 0, 0);
            a_ = __builtin_amdgcn_mfma_f32_16x16x32_bf16(xa[1], b1, a_, 0, 0, 0);
            int c = (nt << 4) + m16;
            int oo = (wv << 1) + (kg >> 1);
            int s = (oo & 8) | ((oo ^ c) & 7);
            uint2 pv2;
            pv2.x = pk2bf(a_[0], a_[1]);
            pv2.y = pk2bf(a_[2], a_[3]);
            *(uint2*)&Vs[(((c << 4) | s) << 3) + ((kg & 1) << 2)] = pv2;
        }
    }
    __syncthreads();   // Epk + Vs ready

    // ---- PV: wave (cp, hq): c-tiles {2cp,2cp+1}, w-tile hq ----
    bf16x8 bE[4];
#pragma unroll
    for (int kt = 0; kt < 4; kt++)
        bE[kt] = *(const bf16x8*)&Epk[(((hq << 2) + kt) * 64 + l) << 3];

    f32x4 acc[2];
    acc[0] = zero4; acc[1] = zero4;
#pragma unroll
    for (int ci = 0; ci < 2; ci++) {
        int ct = cp * 2 + ci;
#pragma unroll
        for (int kt = 0; kt < 4; kt++) {
            int slot = ((ct * 16 + m16) << 4) | ((((kt << 2) | kg)) ^ (m16 & 7));
            bf16x8 aV = *(const bf16x8*)&Vs[slot << 3];
            acc[ci] = __builtin_amdgcn_mfma_f32_16x16x32_bf16(aV, bE[kt], acc[ci], 0, 0, 0);
        }
    }
    f32x4 accS = zero4;
    {
        bf16x8 ones;
        short ov = (m16 == 0) ? (short)0x3F80 : (short)0;
#pragma unroll
        for (int j = 0; j < 8; j++) ones[j] = ov;
#pragma unroll
        for (int kt = 0; kt < 4; kt++)
            accS = __builtin_amdgcn_mfma_f32_16x16x32_bf16(ones, bE[kt], accS, 0, 0, 0);
    }

    float sWv_ = __shfl(accS[0], m16, 64);
    float grv = gm / (sHreg + sWv_);

    // ---- redistribute accHt to (m16,kg) layout via shfls ----
    us4 hA[2];
#pragma unroll
    for (int ci = 0; ci < 2; ci++) {
        int s = (m16 << 2) | ((ci << 1) | (kg >> 1));
        unsigned t0 = __shfl(hAw.x, s, 64), t1 = __shfl(hAw.y, s, 64);
        unsigned t2 = __shfl(hAw.z, s, 64), t3 = __shfl(hAw.w, s, 64);
        unsigned wA = (kg & 1) ? t2 : t0;
        unsigned wB = (kg & 1) ? t3 : t1;
        uint2 uu2;
        uu2.x = wA; uu2.y = wB;
        hA[ci] = *(us4*)&uu2;
    }

    // ---- epilogue: out = grv*(accW+accH) + x (f32 residual from regs) ----
    long obase = ((long)b << 20) + (h << 7) + wfull;
#pragma unroll
    for (int ci = 0; ci < 2; ci++) {
#pragma unroll
        for (int r = 0; r < 4; r++) {
            int c = cp * 32 + ci * 16 + (kg << 2) + r;
            long ga = obase + ((long)c << 14);
            out[ga] = grv * (acc[ci][r] + bf2f(hA[ci][r])) + xr[ci][r];
        }
    }
}

extern "C" void kernel_launch(void* const* d_in, const int* in_sizes, int n_in,
                              void* d_out, int out_size, void* d_ws, size_t ws_size,
                              hipStream_t stream) {
    const float* x     = (const float*)d_in[0];
    const float* Wq    = (const float*)d_in[1];
    const float* bq    = (const float*)d_in[2];
    const float* Wk    = (const float*)d_in[3];
    const float* bk    = (const float*)d_in[4];
    const float* Wv    = (const float*)d_in[5];
    const float* bv    = (const float*)d_in[6];
    const float* gamma = (const float*)d_in[7];
    float* out = (float*)d_out;

    u16* vTc2  = (u16*)d_ws;                 // 16,777,216 u16 (32MB)
    u16* qkTr  = vTc2 + 16777216;            // 4,194,304 u16 (8MB)
    u16* accHt = qkTr + 4194304;             // 16,777,216 u16 (32MB)
    float* sH  = (float*)(accHt + 16777216); // 262,144 f32 (1MB)
    u16* Wpk   = (u16*)(sH + 262144);        // 5,120 u16
    float* biasf = (float*)(Wpk + 5120);     // 80 f32

    wprep_kernel<<<1, 256, 0, stream>>>(Wq, bq, Wk, bk, Wv, bv, Wpk, biasf);
    proj_kernel<<<2048, 256, 0, stream>>>(x, Wpk, biasf, vTc2, qkTr);
    colH_kernel<<<4096, 512, 0, stream>>>(qkTr, vTc2, accHt, sH);
    rowW_fin_kernel<<<4096, 512, 0, stream>>>(qkTr, Wpk, biasf, accHt, sH, x, gamma, out);
}

// Round 21
// 88.570 us; speedup vs baseline: 1.0440x; 1.0440x over previous
//
#include <hip/hip_runtime.h>
#include <hip/hip_bf16.h>
#include <math.h>

// B=16, C=64, CQ=8, H=W=128
typedef unsigned short u16;
typedef unsigned int u32;
typedef __attribute__((ext_vector_type(8))) short    bf16x8;
typedef __attribute__((ext_vector_type(8))) unsigned short us8;
typedef __attribute__((ext_vector_type(4))) unsigned short us4;
typedef __attribute__((ext_vector_type(4))) float    f32x4;
typedef __attribute__((ext_vector_type(4))) unsigned int u32x4;
typedef __attribute__((ext_vector_type(2))) unsigned int u32x2;

__device__ __forceinline__ u16 f2bf(float f) {
    unsigned u = __float_as_uint(f);
    return (u16)((u + 0x7FFFu + ((u >> 16) & 1u)) >> 16);
}
__device__ __forceinline__ float bf2f(u16 v) {
    return __uint_as_float((unsigned)v << 16);
}
// Pack 2 floats -> 2 bf16 (round-half-up) in 3 VALU ops via v_perm_b32.
__device__ __forceinline__ u32 pk2bf(float lo, float hi) {
    u32 a = __float_as_uint(lo) + 0x8000u;
    u32 b = __float_as_uint(hi) + 0x8000u;
    return __builtin_amdgcn_perm(b, a, 0x07060302u);  // [b.b3 b.b2 a.b3 a.b2]
}

// ---------------------------------------------------------------------------
// Kernel 0: W prep. Wpk[nt(5)][kt(2)][lane(64)][8]; biasf[80] = {bv,bq,bk}.
// q rows (n in [64,72)) and bq pre-scaled by log2(e) -> exp2 in attention.
// ---------------------------------------------------------------------------
__global__ __launch_bounds__(256) void wprep_kernel(
    const float* __restrict__ Wq, const float* __restrict__ bq,
    const float* __restrict__ Wk, const float* __restrict__ bk,
    const float* __restrict__ Wv, const float* __restrict__ bv,
    u16* __restrict__ Wpk, float* __restrict__ biasf)
{
    const float LOG2E = 1.44269504088896340736f;
    int t = threadIdx.x;
    for (int s = t; s < 640; s += 256) {
        int nt = s >> 7;
        int kt = (s >> 6) & 1;
        int l  = s & 63;
        int n  = (nt << 4) | (l & 15);
        int k0 = kt * 32 + ((l >> 4) << 3);
        const float* row;
        float sc = 1.0f;
        if (n < 64) row = Wv + n * 64;
        else if (n < 72) { row = Wq + (n - 64) * 64; sc = LOG2E; }
        else row = Wk + (n - 72) * 64;
        us8 o;
#pragma unroll
        for (int j = 0; j < 8; j++) o[j] = f2bf(row[k0 + j] * sc);
        *(us8*)&Wpk[s * 8] = o;
    }
    if (t < 80) {
        float bb;
        if (t < 64) bb = bv[t];
        else if (t < 72) bb = bq[t - 64] * LOG2E;
        else bb = bk[t - 72];
        biasf[t] = bb;
    }
}

// ---------------------------------------------------------------------------
// Kernel 1: projections via MFMA. 8h x 16w tile, 2048 blocks x 256 thr.
// Outputs ONLY vTc2[b][oct][w][c][g8] and qkTr[b][h][w][16].
// ---------------------------------------------------------------------------
__global__ __launch_bounds__(256) void proj_kernel(
    const float* __restrict__ x, const u16* __restrict__ Wpk,
    const float* __restrict__ biasf,
    u16* __restrict__ vTc2, u16* __restrict__ qkTr)
{
    __shared__ u16 vstage[16 * 65 * 8];   // 16.25 KB: [w16][c64+1pad][g8]
    __shared__ u16 qstage[4][32 * 16];    // 4 KB

    int t = threadIdx.x;
    int bid = blockIdx.x;
    int wg = ((bid & 7) << 8) | (bid >> 3);   // bijective (2048 = 8*256)
    int b = wg >> 7;
    int hg = (wg >> 3) & 15;                  // h-oct 0..15
    int wq = wg & 7;
    int h0 = hg << 3, w0 = wq << 4;
    const float* xb = x + ((long)b << 20);

    int wv = t >> 6, l = t & 63;
    int m16 = l & 15, kg = l >> 4;

    // ---- A-frags direct from global: m-tile mt -> h-row h0+wv*2+mt ----
    bf16x8 af[2][2];
#pragma unroll
    for (int mt = 0; mt < 2; mt++) {
        int base = ((h0 + wv * 2 + mt) << 7) + w0 + m16;
#pragma unroll
        for (int kt = 0; kt < 2; kt++) {
            float v[8];
#pragma unroll
            for (int j = 0; j < 8; j++)
                v[j] = xb[((kt * 32 + (kg << 3) + j) << 14) + base];
            u32x4 a4 = { pk2bf(v[0], v[1]), pk2bf(v[2], v[3]),
                         pk2bf(v[4], v[5]), pk2bf(v[6], v[7]) };
            af[mt][kt] = __builtin_bit_cast(bf16x8, a4);
        }
    }

    f32x4 acc[2][5];
#pragma unroll
    for (int nt = 0; nt < 5; nt++) {
        float bb = biasf[(nt << 4) + m16];
        f32x4 binit = {bb, bb, bb, bb};
        bf16x8 b0 = *(const bf16x8*)&Wpk[(((nt << 1) + 0) << 9) + (l << 3)];
        bf16x8 b1 = *(const bf16x8*)&Wpk[(((nt << 1) + 1) << 9) + (l << 3)];
#pragma unroll
        for (int mt = 0; mt < 2; mt++) {
            f32x4 a_ = binit;
            a_ = __builtin_amdgcn_mfma_f32_16x16x32_bf16(af[mt][0], b0, a_, 0, 0, 0);
            a_ = __builtin_amdgcn_mfma_f32_16x16x32_bf16(af[mt][1], b1, a_, 0, 0, 0);
            acc[mt][nt] = a_;
        }
    }

    // ---- vstage: u32 = {g=wv*2 (mt0), g=wv*2+1 (mt1)} at [wl][c] ----
#pragma unroll
    for (int nt = 0; nt < 4; nt++) {
#pragma unroll
        for (int r = 0; r < 4; r++) {
            int c = (nt << 4) + m16;
            int wl = (kg << 2) + r;
            u32 pkv = pk2bf(acc[0][nt][r], acc[1][nt][r]);
            *(u32*)((char*)vstage + wl * 1040 + c * 16 + wv * 4) = pkv;
        }
    }

    // ---- qk: wave-local LDS transpose -> 2x512B coalesced stores ----
    {
        u16* qs = qstage[wv];
#pragma unroll
        for (int mt = 0; mt < 2; mt++) {
#pragma unroll
            for (int r = 0; r < 4; r++)
                qs[((mt << 4) + (kg << 2) + r) * 16 + m16] = f2bf(acc[mt][4][r]);
        }
        int pixl = l >> 1, half = l & 1;
        us8 o = *(us8*)&qs[pixl * 16 + half * 8];
        int hgl = h0 + wv * 2 + (pixl >> 4);
        int wgl = w0 + (pixl & 15);
        *(us8*)&qkTr[(((long)((b << 14) + hgl * 128 + wgl)) << 4) + half * 8] = o;
    }
    __syncthreads();

    // ---- vTc2 write-out: 4 iters, 1KB contiguous per wave-instr ----
#pragma unroll
    for (int u = 0; u < 4; u++) {
        int lin = (u << 8) + t;
        int c = lin & 63, wl = lin >> 6;
        us8 vv = *(const us8*)((char*)vstage + wl * 1040 + c * 16);
        long dst = ((((long)(b * 16 + hg)) * 128 + w0 + wl) * 64 + c) << 3;
        *(us8*)&vTc2[dst] = vv;
    }
}

// ---------------------------------------------------------------------------
// Kernel 3: column attention, h-split. Block (b, w, hh); 4096 blocks.
// (R18 structure: Vs staged before first barrier.)
// ---------------------------------------------------------------------------
__global__ __launch_bounds__(512) void colH_kernel(
    const u16* __restrict__ qkTr, const u16* __restrict__ vTc2,
    u16* __restrict__ accHt, float* __restrict__ sH)
{
    __shared__ u16 Qpk[65 * 8];
    __shared__ u16 Kpk[129 * 8];
    __shared__ u16 Epk[1024 * 8];      // 16 KB
    __shared__ u16 Vs[1024 * 8];       // 16 KB

    int t = threadIdx.x;
    int bid = blockIdx.x;
    int wg = ((bid & 7) << 9) | (bid >> 3);
    int b = wg >> 8, w = (wg >> 1) & 127, hh = wg & 1;
    int h0 = hh << 6;

    if (t < 64) {
        const u16* p = qkTr + (((long)((b << 14) + (h0 + t) * 128 + w)) << 4);
        *(us8*)&Qpk[t * 8] = *(const us8*)p;
    } else if (t == 64) {
        us8 z = {0,0,0,0,0,0,0,0};
        *(us8*)&Qpk[64 * 8] = z;
    } else if (t >= 128 && t < 256) {
        const u16* p = qkTr + (((long)((b << 14) + (t - 128) * 128 + w)) << 4);
        *(us8*)&Kpk[(t - 128) * 8] = *(const us8*)(p + 8);
    } else if (t == 256) {
        us8 z = {0,0,0,0,0,0,0,0};
        *(us8*)&Kpk[128 * 8] = z;
    }

#pragma unroll
    for (int m = t; m < 1024; m += 512) {
        int c = m >> 4, s = m & 15;
        int oct = (s & 8) | ((s ^ c) & 7);
        const u16* srcp = vTc2 + ((((long)(b * 16 + oct)) * 128 + w) * 64 + c) * 8;
        *(us8*)&Vs[m << 3] = *(const us8*)srcp;
    }
    __syncthreads();

    int wv = t >> 6, l = t & 63;
    int m16 = l & 15, kg = l >> 4;
    f32x4 zero4 = {0.f, 0.f, 0.f, 0.f};

    // ---- QK^T: wave owns g-tile gt=wv; E[g][h0+ht*16+m16], 4 ht ----
    int gt = wv;
    bf16x8 afr;
    { int sl = (kg == 0) ? (gt * 16 + m16) : 128;
      afr = *(const bf16x8*)&Kpk[sl * 8]; }
    int kgr = ((gt & 1) << 1) | (kg >> 1);
    int jb  = (kg & 1) << 2;
    int gbase = gt * 16 + kg * 4;
#pragma unroll
    for (int ht = 0; ht < 4; ht++) {
        int slB = (kg == 0) ? (ht * 16 + m16) : 64;
        bf16x8 bfr = *(const bf16x8*)&Qpk[slB * 8];
        f32x4 e = __builtin_amdgcn_mfma_f32_16x16x32_bf16(afr, bfr, zero4, 0, 0, 0);
        float vf[4];
#pragma unroll
        for (int r = 0; r < 4; r++) {
            int g = gbase + r, h = h0 + ht * 16 + m16;
            vf[r] = (g == h) ? 0.f : exp2f(e[r]);
        }
        int eidx = ((((ht << 2) | (gt >> 1)) * 64 + kgr * 16 + m16) << 3) + jb;
        u32x2 pk2;
        pk2.x = pk2bf(vf[0], vf[1]);
        pk2.y = pk2bf(vf[2], vf[3]);
        *(u32x2*)&Epk[eidx] = pk2;
    }
    __syncthreads();

    // ---- PV: wave (cp, hq): c-tiles {2cp,2cp+1}, h-tile hq ----
    int cp = wv >> 2, hq = wv & 3;
    bf16x8 bE[4];
#pragma unroll
    for (int kt = 0; kt < 4; kt++)
        bE[kt] = *(const bf16x8*)&Epk[(((hq << 2) + kt) * 64 + l) << 3];

    f32x4 acc[2];
    acc[0] = zero4; acc[1] = zero4;
#pragma unroll
    for (int ci = 0; ci < 2; ci++) {
        int ct = cp * 2 + ci;
#pragma unroll
        for (int kt = 0; kt < 4; kt++) {
            int slot = ((ct * 16 + m16) << 4) | ((((kt << 2) | kg)) ^ (m16 & 7));
            bf16x8 aV = *(const bf16x8*)&Vs[slot << 3];
            acc[ci] = __builtin_amdgcn_mfma_f32_16x16x32_bf16(aV, bE[kt], acc[ci], 0, 0, 0);
        }
    }
    f32x4 accS = zero4;
    if (cp == 0) {
        bf16x8 ones;
        short ov = (m16 == 0) ? (short)0x3F80 : (short)0;
#pragma unroll
        for (int j = 0; j < 8; j++) ones[j] = ov;
#pragma unroll
        for (int kt = 0; kt < 4; kt++)
            accS = __builtin_amdgcn_mfma_f32_16x16x32_bf16(ones, bE[kt], accS, 0, 0, 0);
    }

    // ---- epilogue: shfl-repack -> one us8 store per lane ----
    u32x2 pk[2];
#pragma unroll
    for (int ci = 0; ci < 2; ci++) {
        pk[ci].x = pk2bf(acc[ci][0], acc[ci][1]);
        pk[ci].y = pk2bf(acc[ci][2], acc[ci][3]);
    }
    int q = l & 3, hrow = l >> 2;
    int sA = ((q & 1) << 5) | hrow;
    int sB = sA + 16;
    unsigned a0 = __shfl(pk[0].x, sA, 64), a1 = __shfl(pk[0].y, sA, 64);
    unsigned a2 = __shfl(pk[1].x, sA, 64), a3 = __shfl(pk[1].y, sA, 64);
    unsigned b0 = __shfl(pk[0].x, sB, 64), b1 = __shfl(pk[0].y, sB, 64);
    unsigned b2 = __shfl(pk[1].x, sB, 64), b3 = __shfl(pk[1].y, sB, 64);
    int cisel = q >> 1;
    uint4 o;
    o.x = cisel ? a2 : a0;  o.y = cisel ? a3 : a1;
    o.z = cisel ? b2 : b0;  o.w = cisel ? b3 : b1;
    long oaddr = (((long)(b * 128 + w)) * 128 + h0 + hq * 16 + hrow) * 64
               + cp * 32 + q * 8;
    *(uint4*)&accHt[oaddr] = o;

    if (cp == 0 && kg == 0)
        sH[(b * 128 + w) * 128 + h0 + hq * 16 + m16] = accS[0];
}

// ---------------------------------------------------------------------------
// Kernel 4: row attention + fused finalize + in-block V-compute.
// R18 structure: V-frag loads inside the V-GEMM block (compiler-scheduled),
// pins only on sHreg/hAw/xr; 2 barriers.
// ---------------------------------------------------------------------------
__global__ __launch_bounds__(512) void rowW_fin_kernel(
    const u16* __restrict__ qkTr, const u16* __restrict__ Wpk,
    const float* __restrict__ biasf,
    const u16* __restrict__ accHt, const float* __restrict__ sH,
    const float* __restrict__ x, const float* __restrict__ gamma,
    float* __restrict__ out)
{
    __shared__ u16 Qpk[65 * 8];
    __shared__ u16 Kpk[129 * 8];
    __shared__ u16 Epk[1024 * 8];   // 16 KB
    __shared__ u16 Vs[1024 * 8];    // 16 KB

    int t = threadIdx.x;
    int bid = blockIdx.x;
    int wg = ((bid & 7) << 9) | (bid >> 3);
    int b = wg >> 8, h = (wg >> 1) & 127, wh = wg & 1;
    int w0 = wh << 6;
    float gm = gamma[0];

    int wv = t >> 6, l = t & 63;
    int m16 = l & 15, kg = l >> 4;
    int cp = wv >> 2, hq = wv & 3;
    int wcol = hq * 16 + m16;
    int wfull = w0 + wcol;

    const float* xrow = x + ((long)b << 20) + (h << 7);

    // ---- hoisted finalize loads ----
    float sHreg = sH[((long)(b * 128 + wfull)) * 128 + h];
    uint4 hAw;
    {
        long hb = (((long)(b * 128 + w0 + (hq << 4) + (l >> 2))) * 128 + h) * 64
                + cp * 32 + ((l & 3) << 3);
        hAw = *(const uint4*)&accHt[hb];
    }
    // residual x values (f32, coalesced across m16)
    float xr[2][4];
#pragma unroll
    for (int ci = 0; ci < 2; ci++)
#pragma unroll
        for (int r = 0; r < 4; r++)
            xr[ci][r] = xrow[((long)(cp * 32 + ci * 16 + (kg << 2) + r) << 14) + wfull];

    // ---- staging: Qpk/Kpk ----
    if (t < 64) {
        const u16* p = qkTr + (((long)((b << 14) + h * 128 + w0 + t)) << 4);
        *(us8*)&Qpk[t * 8] = *(const us8*)p;
    } else if (t == 64) {
        us8 z = {0,0,0,0,0,0,0,0};
        *(us8*)&Qpk[64 * 8] = z;
    } else if (t >= 128 && t < 256) {
        const u16* p = qkTr + (((long)((b << 14) + h * 128 + (t - 128))) << 4);
        *(us8*)&Kpk[(t - 128) * 8] = *(const us8*)(p + 8);
    } else if (t == 256) {
        us8 z = {0,0,0,0,0,0,0,0};
        *(us8*)&Kpk[128 * 8] = z;
    }

    f32x4 zero4 = {0.f, 0.f, 0.f, 0.f};

    // ---- V-GEMM: A-frags direct from global (A[m=w][k=c]) ----
    {
        bf16x8 xa[2];
#pragma unroll
        for (int kt = 0; kt < 2; kt++) {
            float v[8];
#pragma unroll
            for (int j = 0; j < 8; j++)
                v[j] = xrow[((long)(kt * 32 + (kg << 3) + j) << 14) + (wv << 4) + m16];
            u32x4 a4 = { pk2bf(v[0], v[1]), pk2bf(v[2], v[3]),
                         pk2bf(v[4], v[5]), pk2bf(v[6], v[7]) };
            xa[kt] = __builtin_bit_cast(bf16x8, a4);
        }
#pragma unroll
        for (int nt = 0; nt < 4; nt++) {
            float bb = biasf[(nt << 4) + m16];
            f32x4 a_ = {bb, bb, bb, bb};
            bf16x8 b0 = *(const bf16x8*)&Wpk[(((nt << 1) + 0) << 9) + (l << 3)];
            bf16x8 b1 = *(const bf16x8*)&Wpk[(((nt << 1) + 1) << 9) + (l << 3)];
            a_ = __builtin_amdgcn_mfma_f32_16x16x32_bf16(xa[0], b0, a_, 0, 0, 0);
            a_ = __builtin_amdgcn_mfma_f32_16x16x32_bf16(xa[1], b1, a_, 0, 0, 0);
            int c = (nt << 4) + m16;
            int oo = (wv << 1) + (kg >> 1);
            int s = (oo & 8) | ((oo ^ c) & 7);
            uint2 pv2;
            pv2.x = pk2bf(a_[0], a_[1]);
            pv2.y = pk2bf(a_[2], a_[3]);
            *(uint2*)&Vs[(((c << 4) | s) << 3) + ((kg & 1) << 2)] = pv2;
        }
    }

    // keep-alive pins (rule #17)
    asm volatile("" :: "v"(sHreg), "v"(hAw.x), "v"(hAw.y), "v"(hAw.z), "v"(hAw.w));
    asm volatile("" :: "v"(xr[0][0]), "v"(xr[0][1]), "v"(xr[0][2]), "v"(xr[0][3]),
                      "v"(xr[1][0]), "v"(xr[1][1]), "v"(xr[1][2]), "v"(xr[1][3]));
    __syncthreads();   // Vs + Qpk/Kpk ready

    // ---- QK^T: wave owns v-tile gt=wv; E[v][w0+ht*16+m16], no mask ----
    int gt = wv;
    bf16x8 afr;
    { int sl = (kg == 0) ? (gt * 16 + m16) : 128;
      afr = *(const bf16x8*)&Kpk[sl * 8]; }
    int kgr = ((gt & 1) << 1) | (kg >> 1);
    int jb  = (kg & 1) << 2;
#pragma unroll
    for (int ht = 0; ht < 4; ht++) {
        int slB = (kg == 0) ? (ht * 16 + m16) : 64;
        bf16x8 bfr = *(const bf16x8*)&Qpk[slB * 8];
        f32x4 e = __builtin_amdgcn_mfma_f32_16x16x32_bf16(afr, bfr, zero4, 0, 0, 0);
        float vf[4];
#pragma unroll
        for (int r = 0; r < 4; r++) vf[r] = exp2f(e[r]);
        int eidx = ((((ht << 2) | (gt >> 1)) * 64 + kgr * 16 + m16) << 3) + jb;
        u32x2 pk2;
        pk2.x = pk2bf(vf[0], vf[1]);
        pk2.y = pk2bf(vf[2], vf[3]);
        *(u32x2*)&Epk[eidx] = pk2;
    }
    __syncthreads();

    // ---- PV: wave (cp, hq): c-tiles {2cp,2cp+1}, w-tile hq ----
    bf16x8 bE[4];
#pragma unroll
    for (int kt = 0; kt < 4; kt++)
        bE[kt] = *(const bf16x8*)&Epk[(((hq << 2) + kt) * 64 + l) << 3];

    f32x4 acc[2];
    acc[0] = zero4; acc[1] = zero4;
#pragma unroll
    for (int ci = 0; ci < 2; ci++) {
        int ct = cp * 2 + ci;
#pragma unroll
        for (int kt = 0; kt < 4; kt++) {
            int slot = ((ct * 16 + m16) << 4) | ((((kt << 2) | kg)) ^ (m16 & 7));
            bf16x8 aV = *(const bf16x8*)&Vs[slot << 3];
            acc[ci] = __builtin_amdgcn_mfma_f32_16x16x32_bf16(aV, bE[kt], acc[ci], 0, 0, 0);
        }
    }
    f32x4 accS = zero4;
    {
        bf16x8 ones;
        short ov = (m16 == 0) ? (short)0x3F80 : (short)0;
#pragma unroll
        for (int j = 0; j < 8; j++) ones[j] = ov;
#pragma unroll
        for (int kt = 0; kt < 4; kt++)
            accS = __builtin_amdgcn_mfma_f32_16x16x32_bf16(ones, bE[kt], accS, 0, 0, 0);
    }

    float sWv_ = __shfl(accS[0], m16, 64);
    float grv = gm / (sHreg + sWv_);

    // ---- redistribute accHt to (m16,kg) layout via shfls ----
    us4 hA[2];
#pragma unroll
    for (int ci = 0; ci < 2; ci++) {
        int s = (m16 << 2) | ((ci << 1) | (kg >> 1));
        unsigned t0 = __shfl(hAw.x, s, 64), t1 = __shfl(hAw.y, s, 64);
        unsigned t2 = __shfl(hAw.z, s, 64), t3 = __shfl(hAw.w, s, 64);
        unsigned wA = (kg & 1) ? t2 : t0;
        unsigned wB = (kg & 1) ? t3 : t1;
        uint2 uu2;
        uu2.x = wA; uu2.y = wB;
        hA[ci] = *(us4*)&uu2;
    }

    // ---- epilogue: out = grv*(accW+accH) + x (f32 residual from regs) ----
    long obase = ((long)b << 20) + (h << 7) + wfull;
#pragma unroll
    for (int ci = 0; ci < 2; ci++) {
#pragma unroll
        for (int r = 0; r < 4; r++) {
            int c = cp * 32 + ci * 16 + (kg << 2) + r;
            long ga = obase + ((long)c << 14);
            out[ga] = grv * (acc[ci][r] + bf2f(hA[ci][r])) + xr[ci][r];
        }
    }
}

extern "C" void kernel_launch(void* const* d_in, const int* in_sizes, int n_in,
                              void* d_out, int out_size, void* d_ws, size_t ws_size,
                              hipStream_t stream) {
    const float* x     = (const float*)d_in[0];
    const float* Wq    = (const float*)d_in[1];
    const float* bq    = (const float*)d_in[2];
    const float* Wk    = (const float*)d_in[3];
    const float* bk    = (const float*)d_in[4];
    const float* Wv    = (const float*)d_in[5];
    const float* bv    = (const float*)d_in[6];
    const float* gamma = (const float*)d_in[7];
    float* out = (float*)d_out;

    u16* vTc2  = (u16*)d_ws;                 // 16,777,216 u16 (32MB)
    u16* qkTr  = vTc2 + 16777216;            // 4,194,304 u16 (8MB)
    u16* accHt = qkTr + 4194304;             // 16,777,216 u16 (32MB)
    float* sH  = (float*)(accHt + 16777216); // 262,144 f32 (1MB)
    u16* Wpk   = (u16*)(sH + 262144);        // 5,120 u16
    float* biasf = (float*)(Wpk + 5120);     // 80 f32

    wprep_kernel<<<1, 256, 0, stream>>>(Wq, bq, Wk, bk, Wv, bv, Wpk, biasf);
    proj_kernel<<<2048, 256, 0, stream>>>(x, Wpk, biasf, vTc2, qkTr);
    colH_kernel<<<4096, 512, 0, stream>>>(qkTr, vTc2, accHt, sH);
    rowW_fin_kernel<<<4096, 512, 0, stream>>>(qkTr, Wpk, biasf, accHt, sH, x, gamma, out);
}

// Round 22
// 83.839 us; speedup vs baseline: 1.1029x; 1.0564x over previous
//
#include <hip/hip_runtime.h>
#include <hip/hip_bf16.h>

// B=16, C=64, CQ=8, H=W=128
typedef unsigned short u16;
typedef unsigned int u32;
typedef __attribute__((ext_vector_type(8))) short    bf16x8;
typedef __attribute__((ext_vector_type(8))) unsigned short us8;
typedef __attribute__((ext_vector_type(4))) unsigned short us4;
typedef __attribute__((ext_vector_type(4))) float    f32x4;
typedef __attribute__((ext_vector_type(4))) unsigned int u32x4;
typedef __attribute__((ext_vector_type(2))) unsigned int u32x2;

#if __has_builtin(__builtin_amdgcn_exp2f)
#define USE_EXP2 1
__device__ __forceinline__ float fexp(float x) { return __builtin_amdgcn_exp2f(x); }
#else
#define USE_EXP2 0
__device__ __forceinline__ float fexp(float x) { return __expf(x); }
#endif

__device__ __forceinline__ u16 f2bf(float f) {
    unsigned u = __float_as_uint(f);
    return (u16)((u + 0x7FFFu + ((u >> 16) & 1u)) >> 16);
}
__device__ __forceinline__ float bf2f(u16 v) {
    return __uint_as_float((unsigned)v << 16);
}
// Pack 2 floats -> 2 bf16 (round-half-up) in 3 VALU ops via v_perm_b32.
__device__ __forceinline__ u32 pk2bf(float lo, float hi) {
    u32 a = __float_as_uint(lo) + 0x8000u;
    u32 b = __float_as_uint(hi) + 0x8000u;
    return __builtin_amdgcn_perm(b, a, 0x07060302u);  // [b.b3 b.b2 a.b3 a.b2]
}

// ---------------------------------------------------------------------------
// Kernel 0: W prep. Wpk[nt(5)][kt(2)][lane(64)][8]; biasf[80] = {bv,bq,bk}.
// If USE_EXP2: q rows and bq pre-scaled by log2(e) -> raw v_exp_f32 later.
// ---------------------------------------------------------------------------
__global__ __launch_bounds__(256) void wprep_kernel(
    const float* __restrict__ Wq, const float* __restrict__ bq,
    const float* __restrict__ Wk, const float* __restrict__ bk,
    const float* __restrict__ Wv, const float* __restrict__ bv,
    u16* __restrict__ Wpk, float* __restrict__ biasf)
{
    const float QS = USE_EXP2 ? 1.44269504088896340736f : 1.0f;
    int t = threadIdx.x;
    for (int s = t; s < 640; s += 256) {
        int nt = s >> 7;
        int kt = (s >> 6) & 1;
        int l  = s & 63;
        int n  = (nt << 4) | (l & 15);
        int k0 = kt * 32 + ((l >> 4) << 3);
        const float* row;
        float sc = 1.0f;
        if (n < 64) row = Wv + n * 64;
        else if (n < 72) { row = Wq + (n - 64) * 64; sc = QS; }
        else row = Wk + (n - 72) * 64;
        us8 o;
#pragma unroll
        for (int j = 0; j < 8; j++) o[j] = f2bf(row[k0 + j] * sc);
        *(us8*)&Wpk[s * 8] = o;
    }
    if (t < 80) {
        float bb;
        if (t < 64) bb = bv[t];
        else if (t < 72) bb = bq[t - 64] * QS;
        else bb = bk[t - 72];
        biasf[t] = bb;
    }
}

// ---------------------------------------------------------------------------
// Kernel 1: projections via MFMA. 8h x 16w tile, 2048 blocks x 256 thr.
// Outputs ONLY vTc2[b][oct][w][c][g8] and qkTr[b][h][w][16].
// ---------------------------------------------------------------------------
__global__ __launch_bounds__(256) void proj_kernel(
    const float* __restrict__ x, const u16* __restrict__ Wpk,
    const float* __restrict__ biasf,
    u16* __restrict__ vTc2, u16* __restrict__ qkTr)
{
    __shared__ u16 vstage[16 * 65 * 8];   // 16.25 KB: [w16][c64+1pad][g8]
    __shared__ u16 qstage[4][32 * 16];    // 4 KB

    int t = threadIdx.x;
    int bid = blockIdx.x;
    int wg = ((bid & 7) << 8) | (bid >> 3);   // bijective (2048 = 8*256)
    int b = wg >> 7;
    int hg = (wg >> 3) & 15;                  // h-oct 0..15
    int wq = wg & 7;
    int h0 = hg << 3, w0 = wq << 4;
    const float* xb = x + ((long)b << 20);

    int wv = t >> 6, l = t & 63;
    int m16 = l & 15, kg = l >> 4;

    // ---- A-frags direct from global: m-tile mt -> h-row h0+wv*2+mt ----
    bf16x8 af[2][2];
#pragma unroll
    for (int mt = 0; mt < 2; mt++) {
        int base = ((h0 + wv * 2 + mt) << 7) + w0 + m16;
#pragma unroll
        for (int kt = 0; kt < 2; kt++) {
            float v[8];
#pragma unroll
            for (int j = 0; j < 8; j++)
                v[j] = xb[((kt * 32 + (kg << 3) + j) << 14) + base];
            u32x4 a4 = { pk2bf(v[0], v[1]), pk2bf(v[2], v[3]),
                         pk2bf(v[4], v[5]), pk2bf(v[6], v[7]) };
            af[mt][kt] = __builtin_bit_cast(bf16x8, a4);
        }
    }

    f32x4 acc[2][5];
#pragma unroll
    for (int nt = 0; nt < 5; nt++) {
        float bb = biasf[(nt << 4) + m16];
        f32x4 binit = {bb, bb, bb, bb};
        bf16x8 b0 = *(const bf16x8*)&Wpk[(((nt << 1) + 0) << 9) + (l << 3)];
        bf16x8 b1 = *(const bf16x8*)&Wpk[(((nt << 1) + 1) << 9) + (l << 3)];
#pragma unroll
        for (int mt = 0; mt < 2; mt++) {
            f32x4 a_ = binit;
            a_ = __builtin_amdgcn_mfma_f32_16x16x32_bf16(af[mt][0], b0, a_, 0, 0, 0);
            a_ = __builtin_amdgcn_mfma_f32_16x16x32_bf16(af[mt][1], b1, a_, 0, 0, 0);
            acc[mt][nt] = a_;
        }
    }

    // ---- vstage: u32 = {g=wv*2 (mt0), g=wv*2+1 (mt1)} at [wl][c] ----
#pragma unroll
    for (int nt = 0; nt < 4; nt++) {
#pragma unroll
        for (int r = 0; r < 4; r++) {
            int c = (nt << 4) + m16;
            int wl = (kg << 2) + r;
            u32 pkv = pk2bf(acc[0][nt][r], acc[1][nt][r]);
            *(u32*)((char*)vstage + wl * 1040 + c * 16 + wv * 4) = pkv;
        }
    }

    // ---- qk: wave-local LDS transpose -> 2x512B coalesced stores ----
    {
        u16* qs = qstage[wv];
#pragma unroll
        for (int mt = 0; mt < 2; mt++) {
#pragma unroll
            for (int r = 0; r < 4; r++)
                qs[((mt << 4) + (kg << 2) + r) * 16 + m16] = f2bf(acc[mt][4][r]);
        }
        int pixl = l >> 1, half = l & 1;
        us8 o = *(us8*)&qs[pixl * 16 + half * 8];
        int hgl = h0 + wv * 2 + (pixl >> 4);
        int wgl = w0 + (pixl & 15);
        *(us8*)&qkTr[(((long)((b << 14) + hgl * 128 + wgl)) << 4) + half * 8] = o;
    }
    __syncthreads();

    // ---- vTc2 write-out: 4 iters, 1KB contiguous per wave-instr ----
#pragma unroll
    for (int u = 0; u < 4; u++) {
        int lin = (u << 8) + t;
        int c = lin & 63, wl = lin >> 6;
        us8 vv = *(const us8*)((char*)vstage + wl * 1040 + c * 16);
        long dst = ((((long)(b * 16 + hg)) * 128 + w0 + wl) * 64 + c) << 3;
        *(us8*)&vTc2[dst] = vv;
    }
}

// ---------------------------------------------------------------------------
// Kernel 3: column attention, h-split. Block (b, w, hh); 4096 blocks.
// ---------------------------------------------------------------------------
__global__ __launch_bounds__(512) void colH_kernel(
    const u16* __restrict__ qkTr, const u16* __restrict__ vTc2,
    u16* __restrict__ accHt, float* __restrict__ sH)
{
    __shared__ u16 Qpk[65 * 8];
    __shared__ u16 Kpk[129 * 8];
    __shared__ u16 Epk[1024 * 8];      // 16 KB
    __shared__ u16 Vs[1024 * 8];       // 16 KB

    int t = threadIdx.x;
    int bid = blockIdx.x;
    int wg = ((bid & 7) << 9) | (bid >> 3);
    int b = wg >> 8, w = (wg >> 1) & 127, hh = wg & 1;
    int h0 = hh << 6;

    if (t < 64) {
        const u16* p = qkTr + (((long)((b << 14) + (h0 + t) * 128 + w)) << 4);
        *(us8*)&Qpk[t * 8] = *(const us8*)p;
    } else if (t == 64) {
        us8 z = {0,0,0,0,0,0,0,0};
        *(us8*)&Qpk[64 * 8] = z;
    } else if (t >= 128 && t < 256) {
        const u16* p = qkTr + (((long)((b << 14) + (t - 128) * 128 + w)) << 4);
        *(us8*)&Kpk[(t - 128) * 8] = *(const us8*)(p + 8);
    } else if (t == 256) {
        us8 z = {0,0,0,0,0,0,0,0};
        *(us8*)&Kpk[128 * 8] = z;
    }

#pragma unroll
    for (int m = t; m < 1024; m += 512) {
        int c = m >> 4, s = m & 15;
        int oct = (s & 8) | ((s ^ c) & 7);
        const u16* srcp = vTc2 + ((((long)(b * 16 + oct)) * 128 + w) * 64 + c) * 8;
        *(us8*)&Vs[m << 3] = *(const us8*)srcp;
    }
    __syncthreads();

    int wv = t >> 6, l = t & 63;
    int m16 = l & 15, kg = l >> 4;
    f32x4 zero4 = {0.f, 0.f, 0.f, 0.f};

    // ---- QK^T: wave owns g-tile gt=wv; E[g][h0+ht*16+m16], 4 ht ----
    int gt = wv;
    bf16x8 afr;
    { int sl = (kg == 0) ? (gt * 16 + m16) : 128;
      afr = *(const bf16x8*)&Kpk[sl * 8]; }
    int kgr = ((gt & 1) << 1) | (kg >> 1);
    int jb  = (kg & 1) << 2;
    int gbase = gt * 16 + kg * 4;
#pragma unroll
    for (int ht = 0; ht < 4; ht++) {
        int slB = (kg == 0) ? (ht * 16 + m16) : 64;
        bf16x8 bfr = *(const bf16x8*)&Qpk[slB * 8];
        f32x4 e = __builtin_amdgcn_mfma_f32_16x16x32_bf16(afr, bfr, zero4, 0, 0, 0);
        float vf[4];
#pragma unroll
        for (int r = 0; r < 4; r++) {
            int g = gbase + r, h = h0 + ht * 16 + m16;
            vf[r] = (g == h) ? 0.f : fexp(e[r]);
        }
        int eidx = ((((ht << 2) | (gt >> 1)) * 64 + kgr * 16 + m16) << 3) + jb;
        u32x2 pk2;
        pk2.x = pk2bf(vf[0], vf[1]);
        pk2.y = pk2bf(vf[2], vf[3]);
        *(u32x2*)&Epk[eidx] = pk2;
    }
    __syncthreads();

    // ---- PV: wave (cp, hq): c-tiles {2cp,2cp+1}, h-tile hq ----
    int cp = wv >> 2, hq = wv & 3;
    bf16x8 bE[4];
#pragma unroll
    for (int kt = 0; kt < 4; kt++)
        bE[kt] = *(const bf16x8*)&Epk[(((hq << 2) + kt) * 64 + l) << 3];

    f32x4 acc[2];
    acc[0] = zero4; acc[1] = zero4;
#pragma unroll
    for (int ci = 0; ci < 2; ci++) {
        int ct = cp * 2 + ci;
#pragma unroll
        for (int kt = 0; kt < 4; kt++) {
            int slot = ((ct * 16 + m16) << 4) | ((((kt << 2) | kg)) ^ (m16 & 7));
            bf16x8 aV = *(const bf16x8*)&Vs[slot << 3];
            acc[ci] = __builtin_amdgcn_mfma_f32_16x16x32_bf16(aV, bE[kt], acc[ci], 0, 0, 0);
        }
    }
    f32x4 accS = zero4;
    if (cp == 0) {
        bf16x8 ones;
        short ov = (m16 == 0) ? (short)0x3F80 : (short)0;
#pragma unroll
        for (int j = 0; j < 8; j++) ones[j] = ov;
#pragma unroll
        for (int kt = 0; kt < 4; kt++)
            accS = __builtin_amdgcn_mfma_f32_16x16x32_bf16(ones, bE[kt], accS, 0, 0, 0);
    }

    // ---- epilogue: shfl-repack -> one us8 store per lane ----
    u32x2 pk[2];
#pragma unroll
    for (int ci = 0; ci < 2; ci++) {
        pk[ci].x = pk2bf(acc[ci][0], acc[ci][1]);
        pk[ci].y = pk2bf(acc[ci][2], acc[ci][3]);
    }
    int q = l & 3, hrow = l >> 2;
    int sA = ((q & 1) << 5) | hrow;
    int sB = sA + 16;
    unsigned a0 = __shfl(pk[0].x, sA, 64), a1 = __shfl(pk[0].y, sA, 64);
    unsigned a2 = __shfl(pk[1].x, sA, 64), a3 = __shfl(pk[1].y, sA, 64);
    unsigned b0 = __shfl(pk[0].x, sB, 64), b1 = __shfl(pk[0].y, sB, 64);
    unsigned b2 = __shfl(pk[1].x, sB, 64), b3 = __shfl(pk[1].y, sB, 64);
    int cisel = q >> 1;
    uint4 o;
    o.x = cisel ? a2 : a0;  o.y = cisel ? a3 : a1;
    o.z = cisel ? b2 : b0;  o.w = cisel ? b3 : b1;
    long oaddr = (((long)(b * 128 + w)) * 128 + h0 + hq * 16 + hrow) * 64
               + cp * 32 + q * 8;
    *(uint4*)&accHt[oaddr] = o;

    if (cp == 0 && kg == 0)
        sH[(b * 128 + w) * 128 + h0 + hq * 16 + m16] = accS[0];
}

// ---------------------------------------------------------------------------
// Kernel 4: row attention + fused finalize + in-block V-compute.
// R18 structure: V-frag loads inside the V-GEMM block (compiler-scheduled),
// pins only on sHreg/hAw/xr; 2 barriers.
// ---------------------------------------------------------------------------
__global__ __launch_bounds__(512) void rowW_fin_kernel(
    const u16* __restrict__ qkTr, const u16* __restrict__ Wpk,
    const float* __restrict__ biasf,
    const u16* __restrict__ accHt, const float* __restrict__ sH,
    const float* __restrict__ x, const float* __restrict__ gamma,
    float* __restrict__ out)
{
    __shared__ u16 Qpk[65 * 8];
    __shared__ u16 Kpk[129 * 8];
    __shared__ u16 Epk[1024 * 8];   // 16 KB
    __shared__ u16 Vs[1024 * 8];    // 16 KB

    int t = threadIdx.x;
    int bid = blockIdx.x;
    int wg = ((bid & 7) << 9) | (bid >> 3);
    int b = wg >> 8, h = (wg >> 1) & 127, wh = wg & 1;
    int w0 = wh << 6;
    float gm = gamma[0];

    int wv = t >> 6, l = t & 63;
    int m16 = l & 15, kg = l >> 4;
    int cp = wv >> 2, hq = wv & 3;
    int wcol = hq * 16 + m16;
    int wfull = w0 + wcol;

    const float* xrow = x + ((long)b << 20) + (h << 7);

    // ---- hoisted finalize loads ----
    float sHreg = sH[((long)(b * 128 + wfull)) * 128 + h];
    uint4 hAw;
    {
        long hb = (((long)(b * 128 + w0 + (hq << 4) + (l >> 2))) * 128 + h) * 64
                + cp * 32 + ((l & 3) << 3);
        hAw = *(const uint4*)&accHt[hb];
    }
    // residual x values (f32, coalesced across m16)
    float xr[2][4];
#pragma unroll
    for (int ci = 0; ci < 2; ci++)
#pragma unroll
        for (int r = 0; r < 4; r++)
            xr[ci][r] = xrow[((long)(cp * 32 + ci * 16 + (kg << 2) + r) << 14) + wfull];

    // ---- staging: Qpk/Kpk ----
    if (t < 64) {
        const u16* p = qkTr + (((long)((b << 14) + h * 128 + w0 + t)) << 4);
        *(us8*)&Qpk[t * 8] = *(const us8*)p;
    } else if (t == 64) {
        us8 z = {0,0,0,0,0,0,0,0};
        *(us8*)&Qpk[64 * 8] = z;
    } else if (t >= 128 && t < 256) {
        const u16* p = qkTr + (((long)((b << 14) + h * 128 + (t - 128))) << 4);
        *(us8*)&Kpk[(t - 128) * 8] = *(const us8*)(p + 8);
    } else if (t == 256) {
        us8 z = {0,0,0,0,0,0,0,0};
        *(us8*)&Kpk[128 * 8] = z;
    }

    f32x4 zero4 = {0.f, 0.f, 0.f, 0.f};

    // ---- V-GEMM: A-frags direct from global (A[m=w][k=c]) ----
    {
        bf16x8 xa[2];
#pragma unroll
        for (int kt = 0; kt < 2; kt++) {
            float v[8];
#pragma unroll
            for (int j = 0; j < 8; j++)
                v[j] = xrow[((long)(kt * 32 + (kg << 3) + j) << 14) + (wv << 4) + m16];
            u32x4 a4 = { pk2bf(v[0], v[1]), pk2bf(v[2], v[3]),
                         pk2bf(v[4], v[5]), pk2bf(v[6], v[7]) };
            xa[kt] = __builtin_bit_cast(bf16x8, a4);
        }
#pragma unroll
        for (int nt = 0; nt < 4; nt++) {
            float bb = biasf[(nt << 4) + m16];
            f32x4 a_ = {bb, bb, bb, bb};
            bf16x8 b0 = *(const bf16x8*)&Wpk[(((nt << 1) + 0) << 9) + (l << 3)];
            bf16x8 b1 = *(const bf16x8*)&Wpk[(((nt << 1) + 1) << 9) + (l << 3)];
            a_ = __builtin_amdgcn_mfma_f32_16x16x32_bf16(xa[0], b0, a_, 0, 0, 0);
            a_ = __builtin_amdgcn_mfma_f32_16x16x32_bf16(xa[1], b1, a_, 0, 0, 0);
            int c = (nt << 4) + m16;
            int oo = (wv << 1) + (kg >> 1);
            int s = (oo & 8) | ((oo ^ c) & 7);
            uint2 pv2;
            pv2.x = pk2bf(a_[0], a_[1]);
            pv2.y = pk2bf(a_[2], a_[3]);
            *(uint2*)&Vs[(((c << 4) | s) << 3) + ((kg & 1) << 2)] = pv2;
        }
    }

    // keep-alive pins (rule #17)
    asm volatile("" :: "v"(sHreg), "v"(hAw.x), "v"(hAw.y), "v"(hAw.z), "v"(hAw.w));
    asm volatile("" :: "v"(xr[0][0]), "v"(xr[0][1]), "v"(xr[0][2]), "v"(xr[0][3]),
                      "v"(xr[1][0]), "v"(xr[1][1]), "v"(xr[1][2]), "v"(xr[1][3]));
    __syncthreads();   // Vs + Qpk/Kpk ready

    // ---- QK^T: wave owns v-tile gt=wv; E[v][w0+ht*16+m16], no mask ----
    int gt = wv;
    bf16x8 afr;
    { int sl = (kg == 0) ? (gt * 16 + m16) : 128;
      afr = *(const bf16x8*)&Kpk[sl * 8]; }
    int kgr = ((gt & 1) << 1) | (kg >> 1);
    int jb  = (kg & 1) << 2;
#pragma unroll
    for (int ht = 0; ht < 4; ht++) {
        int slB = (kg == 0) ? (ht * 16 + m16) : 64;
        bf16x8 bfr = *(const bf16x8*)&Qpk[slB * 8];
        f32x4 e = __builtin_amdgcn_mfma_f32_16x16x32_bf16(afr, bfr, zero4, 0, 0, 0);
        float vf[4];
#pragma unroll
        for (int r = 0; r < 4; r++) vf[r] = fexp(e[r]);
        int eidx = ((((ht << 2) | (gt >> 1)) * 64 + kgr * 16 + m16) << 3) + jb;
        u32x2 pk2;
        pk2.x = pk2bf(vf[0], vf[1]);
        pk2.y = pk2bf(vf[2], vf[3]);
        *(u32x2*)&Epk[eidx] = pk2;
    }
    __syncthreads();

    // ---- PV: wave (cp, hq): c-tiles {2cp,2cp+1}, w-tile hq ----
    bf16x8 bE[4];
#pragma unroll
    for (int kt = 0; kt < 4; kt++)
        bE[kt] = *(const bf16x8*)&Epk[(((hq << 2) + kt) * 64 + l) << 3];

    f32x4 acc[2];
    acc[0] = zero4; acc[1] = zero4;
#pragma unroll
    for (int ci = 0; ci < 2; ci++) {
        int ct = cp * 2 + ci;
#pragma unroll
        for (int kt = 0; kt < 4; kt++) {
            int slot = ((ct * 16 + m16) << 4) | ((((kt << 2) | kg)) ^ (m16 & 7));
            bf16x8 aV = *(const bf16x8*)&Vs[slot << 3];
            acc[ci] = __builtin_amdgcn_mfma_f32_16x16x32_bf16(aV, bE[kt], acc[ci], 0, 0, 0);
        }
    }
    f32x4 accS = zero4;
    {
        bf16x8 ones;
        short ov = (m16 == 0) ? (short)0x3F80 : (short)0;
#pragma unroll
        for (int j = 0; j < 8; j++) ones[j] = ov;
#pragma unroll
        for (int kt = 0; kt < 4; kt++)
            accS = __builtin_amdgcn_mfma_f32_16x16x32_bf16(ones, bE[kt], accS, 0, 0, 0);
    }

    float sWv_ = __shfl(accS[0], m16, 64);
    float grv = gm / (sHreg + sWv_);

    // ---- redistribute accHt to (m16,kg) layout via shfls ----
    us4 hA[2];
#pragma unroll
    for (int ci = 0; ci < 2; ci++) {
        int s = (m16 << 2) | ((ci << 1) | (kg >> 1));
        unsigned t0 = __shfl(hAw.x, s, 64), t1 = __shfl(hAw.y, s, 64);
        unsigned t2 = __shfl(hAw.z, s, 64), t3 = __shfl(hAw.w, s, 64);
        unsigned wA = (kg & 1) ? t2 : t0;
        unsigned wB = (kg & 1) ? t3 : t1;
        uint2 uu2;
        uu2.x = wA; uu2.y = wB;
        hA[ci] = *(us4*)&uu2;
    }

    // ---- epilogue: out = grv*(accW+accH) + x (f32 residual from regs) ----
    long obase = ((long)b << 20) + (h << 7) + wfull;
#pragma unroll
    for (int ci = 0; ci < 2; ci++) {
#pragma unroll
        for (int r = 0; r < 4; r++) {
            int c = cp * 32 + ci * 16 + (kg << 2) + r;
            long ga = obase + ((long)c << 14);
            out[ga] = grv * (acc[ci][r] + bf2f(hA[ci][r])) + xr[ci][r];
        }
    }
}

extern "C" void kernel_launch(void* const* d_in, const int* in_sizes, int n_in,
                              void* d_out, int out_size, void* d_ws, size_t ws_size,
                              hipStream_t stream) {
    const float* x     = (const float*)d_in[0];
    const float* Wq    = (const float*)d_in[1];
    const float* bq    = (const float*)d_in[2];
    const float* Wk    = (const float*)d_in[3];
    const float* bk    = (const float*)d_in[4];
    const float* Wv    = (const float*)d_in[5];
    const float* bv    = (const float*)d_in[6];
    const float* gamma = (const float*)d_in[7];
    float* out = (float*)d_out;

    u16* vTc2  = (u16*)d_ws;                 // 16,777,216 u16 (32MB)
    u16* qkTr  = vTc2 + 16777216;            // 4,194,304 u16 (8MB)
    u16* accHt = qkTr + 4194304;             // 16,777,216 u16 (32MB)
    float* sH  = (float*)(accHt + 16777216); // 262,144 f32 (1MB)
    u16* Wpk   = (u16*)(sH + 262144);        // 5,120 u16
    float* biasf = (float*)(Wpk + 5120);     // 80 f32

    wprep_kernel<<<1, 256, 0, stream>>>(Wq, bq, Wk, bk, Wv, bv, Wpk, biasf);
    proj_kernel<<<2048, 256, 0, stream>>>(x, Wpk, biasf, vTc2, qkTr);
    colH_kernel<<<4096, 512, 0, stream>>>(qkTr, vTc2, accHt, sH);
    rowW_fin_kernel<<<4096, 512, 0, stream>>>(qkTr, Wpk, biasf, accHt, sH, x, gamma, out);
}